// Round 1
// baseline (1605.246 us; speedup 1.0000x reference)
//
#include <hip/hip_runtime.h>

// RGT layer: att = (qrh·(g1[src]+M1@eh) + qeh·(g2[src]+M2@eh))/8
//   g1[n]=A1@h[n], g2[n]=A2@h[n], A1=Wq_top Wk_top^T, A2=Wq_bot Wk_top^T,
//   M1=Wq_top Wk_bot^T, M2=Wq_bot Wk_bot^T   (verified algebra, see derivation)
// msg = leaky(hm[src] + eh@Wmsg_bot), hm[n]=h[n]@Wmsg_top
// CSR by dst -> per-node wave: softmax, aggregate, W_out GEMV, +h, LN, deg mask.

#define D 64
#define NEG 0.01f
#define LN_EPS 1e-6f

__device__ __forceinline__ float wred_sum(float v){
#pragma unroll
  for (int off = 32; off > 0; off >>= 1) v += __shfl_xor(v, off, 64);
  return v;
}
__device__ __forceinline__ float wred_max(float v){
#pragma unroll
  for (int off = 32; off > 0; off >>= 1) v = fmaxf(v, __shfl_xor(v, off, 64));
  return v;
}
__device__ __forceinline__ void lds_fence(){
  asm volatile("s_waitcnt lgkmcnt(0)" ::: "memory");
}

// ---------------- setup: 4 derived 64x64 matrices, stored transposed (m-major)
__global__ void k_setup(const float* __restrict__ Wq, const float* __restrict__ Wk,
                        float* __restrict__ A1T, float* __restrict__ A2T,
                        float* __restrict__ M1T, float* __restrict__ M2T){
  int t = blockIdx.x * blockDim.x + threadIdx.x;
  if (t >= 64 * 64) return;
  int i = t & 63, m = t >> 6;
  float a1 = 0.f, a2 = 0.f, m1 = 0.f, m2 = 0.f;
  for (int o = 0; o < 64; ++o){
    float wqt = Wq[i * 64 + o], wqb = Wq[(64 + i) * 64 + o];
    float wkt = Wk[m * 64 + o], wkb = Wk[(64 + m) * 64 + o];
    a1 = fmaf(wqt, wkt, a1); a2 = fmaf(wqb, wkt, a2);
    m1 = fmaf(wqt, wkb, m1); m2 = fmaf(wqb, wkb, m2);
  }
  A1T[m * 64 + i] = a1; A2T[m * 64 + i] = a2;
  M1T[m * 64 + i] = m1; M2T[m * 64 + i] = m2;
}

// ---------------- node precompute: g1 = h@A1^T, g2 = h@A2^T, hm = h@Wmsg_top
__global__ void __launch_bounds__(256) k_node_pre(
    int N, const float* __restrict__ h, const float* __restrict__ A1T,
    const float* __restrict__ A2T, const float* __restrict__ Wmsg,
    float* __restrict__ g1, float* __restrict__ g2, float* __restrict__ hm){
  __shared__ float sA1[4096], sA2[4096], sW[4096];
  __shared__ __align__(16) float hbuf[4][4][64];
  for (int t = threadIdx.x; t < 4096; t += 256){
    sA1[t] = A1T[t]; sA2[t] = A2T[t]; sW[t] = Wmsg[t];  // Wmsg rows 0..63 = top
  }
  __syncthreads();
  int wid = threadIdx.x >> 6, lane = threadIdx.x & 63;
  int wglob = blockIdx.x * 4 + wid, nw = gridDim.x * 4;
  for (int n0 = wglob * 4; n0 < N; n0 += nw * 4){
    lds_fence();
#pragma unroll
    for (int b = 0; b < 4; ++b){
      int n = n0 + b;
      hbuf[wid][b][lane] = (n < N) ? h[n * 64 + lane] : 0.f;
    }
    __builtin_amdgcn_wave_barrier();
    lds_fence();
    float ac1[4] = {0,0,0,0}, ac2[4] = {0,0,0,0}, ac3[4] = {0,0,0,0};
    for (int m = 0; m < 64; ++m){
      float a1 = sA1[m * 64 + lane], a2 = sA2[m * 64 + lane], wm = sW[m * 64 + lane];
#pragma unroll
      for (int b = 0; b < 4; ++b){
        float hv = hbuf[wid][b][m];
        ac1[b] = fmaf(a1, hv, ac1[b]);
        ac2[b] = fmaf(a2, hv, ac2[b]);
        ac3[b] = fmaf(wm, hv, ac3[b]);
      }
    }
#pragma unroll
    for (int b = 0; b < 4; ++b){
      int n = n0 + b;
      if (n < N){
        g1[n * 64 + lane] = ac1[b];
        g2[n * 64 + lane] = ac2[b];
        hm[n * 64 + lane] = ac3[b];
      }
    }
    __builtin_amdgcn_wave_barrier();
  }
}

// ---------------- degree histogram
__global__ void k_count(int E, const int* __restrict__ dst, unsigned int* __restrict__ deg){
  int e = blockIdx.x * blockDim.x + threadIdx.x;
  int stride = gridDim.x * blockDim.x;
  for (; e < E; e += stride) atomicAdd(&deg[dst[e]], 1u);
}

// ---------------- single-block exclusive scan -> rowptr, cursor
__global__ void __launch_bounds__(1024) k_scan(
    int N, const unsigned int* __restrict__ deg,
    unsigned int* __restrict__ rowptr, unsigned int* __restrict__ cursor){
  __shared__ unsigned int part[1024];
  int t = threadIdx.x;
  int CH = (N + 1023) >> 10;
  int lo = t * CH, hi = min(lo + CH, N);
  unsigned int s = 0;
  for (int i = lo; i < hi; ++i) s += deg[i];
  part[t] = s;
  __syncthreads();
  for (int off = 1; off < 1024; off <<= 1){
    unsigned int v = (t >= off) ? part[t - off] : 0u;
    __syncthreads();
    part[t] += v;
    __syncthreads();
  }
  unsigned int run = (t > 0) ? part[t - 1] : 0u;
  for (int i = lo; i < hi; ++i){
    rowptr[i] = run; cursor[i] = run;
    run += deg[i];
  }
  if (t == 1023) rowptr[N] = part[1023];
}

// ---------------- edge pass: attention logits + CSR scatter
// lane = i. M1,M2 rows held in VGPRs (w1[m]=M1[i,m]). eh row broadcast via LDS.
__global__ void __launch_bounds__(256) k_edge(
    int E, const float* __restrict__ eh, const float* __restrict__ qrh,
    const float* __restrict__ qeh, const int* __restrict__ src,
    const int* __restrict__ dst, const float* __restrict__ g1,
    const float* __restrict__ g2, const float* __restrict__ M1T,
    const float* __restrict__ M2T, float* __restrict__ att,
    unsigned int* __restrict__ cursor, int* __restrict__ eidx){
  __shared__ __align__(16) float ebuf[4][2][64];
  int wid = threadIdx.x >> 6, lane = threadIdx.x & 63;
  float w1[64], w2[64];
#pragma unroll
  for (int m = 0; m < 64; ++m){
    w1[m] = M1T[m * 64 + lane];
    w2[m] = M2T[m * 64 + lane];
  }
  int wglob = blockIdx.x * 4 + wid, nw = gridDim.x * 4;
  int e = wglob;
  if (e >= E) return;
  int se = src[e], de = dst[e];
  float q1v = qrh[e * 64 + lane], q2v = qeh[e * 64 + lane];
  float g1v = g1[se * 64 + lane], g2v = g2[se * 64 + lane];
  ebuf[wid][0][lane] = eh[e * 64 + lane];
  int cur = 0;
  while (true){
    int en = e + nw;
    bool has_next = (en < E);
    int sn = 0, dn = 0;
    float q1n = 0.f, q2n = 0.f, g1n = 0.f, g2n = 0.f;
    lds_fence();  // WAR: prior reads of ebuf[cur^1] done before overwrite
    if (has_next){
      sn = src[en]; dn = dst[en];
      q1n = qrh[en * 64 + lane]; q2n = qeh[en * 64 + lane];
      g1n = g1[sn * 64 + lane];  g2n = g2[sn * 64 + lane];
      ebuf[wid][cur ^ 1][lane] = eh[en * 64 + lane];
    }
    __builtin_amdgcn_wave_barrier();
    // GEMV on current edge: t1 = M1@eh, t2 = M2@eh  (2x2 split chains for ILP)
    float t1a = 0.f, t1b = 0.f, t2a = 0.f, t2b = 0.f;
    const float4* sh4 = (const float4*)ebuf[wid][cur];
#pragma unroll
    for (int m4 = 0; m4 < 16; ++m4){
      float4 ev = sh4[m4];
      t1a = fmaf(ev.x, w1[4 * m4 + 0], t1a); t2a = fmaf(ev.x, w2[4 * m4 + 0], t2a);
      t1b = fmaf(ev.y, w1[4 * m4 + 1], t1b); t2b = fmaf(ev.y, w2[4 * m4 + 1], t2b);
      t1a = fmaf(ev.z, w1[4 * m4 + 2], t1a); t2a = fmaf(ev.z, w2[4 * m4 + 2], t2a);
      t1b = fmaf(ev.w, w1[4 * m4 + 3], t1b); t2b = fmaf(ev.w, w2[4 * m4 + 3], t2b);
    }
    float partv = q1v * (g1v + t1a + t1b) + q2v * (g2v + t2a + t2b);
    float s = wred_sum(partv) * 0.125f;
    if (lane == 0){
      att[e] = s;
      unsigned int pos = atomicAdd(&cursor[de], 1u);
      eidx[pos] = e;
    }
    if (!has_next) break;
    e = en; se = sn; de = dn;
    q1v = q1n; q2v = q2n; g1v = g1n; g2v = g2n;
    cur ^= 1;
    __builtin_amdgcn_wave_barrier();
  }
}

// ---------------- node pass: softmax + aggregate + W_out GEMV + LN + mask
__global__ void __launch_bounds__(256) k_node(
    int N, const float* __restrict__ h, const float* __restrict__ eh,
    const int* __restrict__ src, const float* __restrict__ hm,
    const float* __restrict__ att, const unsigned int* __restrict__ rowptr,
    const int* __restrict__ eidx, const float* __restrict__ Wmsg,
    const float* __restrict__ Wout, const float* __restrict__ gamma,
    const float* __restrict__ beta, float* __restrict__ out){
  __shared__ float sWout[4096];
  __shared__ __align__(16) float ebuf[4][2][64];
  __shared__ __align__(16) float aggbuf[4][64];
  for (int t = threadIdx.x; t < 4096; t += 256) sWout[t] = Wout[t];
  __syncthreads();
  int wid = threadIdx.x >> 6, lane = threadIdx.x & 63;
  float wmsg[64];
#pragma unroll
  for (int m = 0; m < 64; ++m) wmsg[m] = Wmsg[(64 + m) * 64 + lane];  // bottom half
  float gam = gamma[lane], bet = beta[lane];
  int wglob = blockIdx.x * 4 + wid, nw = gridDim.x * 4;
  for (int n = wglob; n < N; n += nw){
    unsigned int rb = rowptr[n], re = rowptr[n + 1];
    if (re == rb){  // no incoming edges: pass h through
      out[n * 64 + lane] = h[n * 64 + lane];
      continue;
    }
    float mloc = -1e30f;
    for (unsigned int b = rb; b < re; b += 64){
      unsigned int idx = b + lane;
      if (idx < re) mloc = fmaxf(mloc, att[eidx[idx]]);
    }
    float mmax = wred_max(mloc);
    float sloc = 0.f;
    for (unsigned int b = rb; b < re; b += 64){
      unsigned int idx = b + lane;
      if (idx < re) sloc += __expf(att[eidx[idx]] - mmax);
    }
    float denom = wred_sum(sloc);
    // aggregation with 1-deep prefetch
    float acc = 0.f;
    int eid = eidx[rb];
    int s0 = src[eid];
    float a0 = att[eid];
    float hmv = hm[s0 * 64 + lane];
    ebuf[wid][0][lane] = eh[eid * 64 + lane];
    int cur = 0;
    for (unsigned int t = rb; t < re; ++t){
      bool hn_ = (t + 1 < re);
      int eidN = 0, sN = 0;
      float aN = 0.f, hmN = 0.f;
      lds_fence();
      if (hn_){
        eidN = eidx[t + 1]; sN = src[eidN];
        aN = att[eidN];
        ebuf[wid][cur ^ 1][lane] = eh[eidN * 64 + lane];
        hmN = hm[sN * 64 + lane];
      }
      __builtin_amdgcn_wave_barrier();
      float p = __expf(a0 - mmax);
      float mv0 = hmv, mv1 = 0.f;
      const float4* sh4 = (const float4*)ebuf[wid][cur];
#pragma unroll
      for (int m4 = 0; m4 < 16; ++m4){
        float4 ev = sh4[m4];
        mv0 = fmaf(ev.x, wmsg[4 * m4 + 0], mv0);
        mv1 = fmaf(ev.y, wmsg[4 * m4 + 1], mv1);
        mv0 = fmaf(ev.z, wmsg[4 * m4 + 2], mv0);
        mv1 = fmaf(ev.w, wmsg[4 * m4 + 3], mv1);
      }
      float mv = mv0 + mv1;
      float lv = (mv > 0.f) ? mv : NEG * mv;
      acc = fmaf(p, lv, acc);
      a0 = aN; hmv = hmN; cur ^= 1;
      __builtin_amdgcn_wave_barrier();
    }
    float agg = acc / denom;
    lds_fence();
    aggbuf[wid][lane] = agg;
    __builtin_amdgcn_wave_barrier();
    lds_fence();
    // out_o = sum_j agg_j * Wout[j,o]
    float t0a = 0.f, t0b = 0.f;
    const float4* ab4 = (const float4*)aggbuf[wid];
#pragma unroll
    for (int j4 = 0; j4 < 16; ++j4){
      float4 av = ab4[j4];
      t0a = fmaf(av.x, sWout[(4 * j4 + 0) * 64 + lane], t0a);
      t0b = fmaf(av.y, sWout[(4 * j4 + 1) * 64 + lane], t0b);
      t0a = fmaf(av.z, sWout[(4 * j4 + 2) * 64 + lane], t0a);
      t0b = fmaf(av.w, sWout[(4 * j4 + 3) * 64 + lane], t0b);
    }
    float t0 = t0a + t0b;
    float hnv = ((t0 > 0.f) ? t0 : NEG * t0) + h[n * 64 + lane];
    float mu = wred_sum(hnv) * (1.f / 64.f);
    float dv = hnv - mu;
    float var = wred_sum(dv * dv) * (1.f / 64.f);
    float ln = dv * (1.f / sqrtf(var + LN_EPS)) * gam + bet;
    out[n * 64 + lane] = ln;
    __builtin_amdgcn_wave_barrier();
  }
}

extern "C" void kernel_launch(void* const* d_in, const int* in_sizes, int n_in,
                              void* d_out, int out_size, void* d_ws, size_t ws_size,
                              hipStream_t stream){
  const float* h    = (const float*)d_in[0];
  const float* eh   = (const float*)d_in[1];
  const float* qrh  = (const float*)d_in[2];
  const float* qeh  = (const float*)d_in[3];
  const int*   src  = (const int*)d_in[4];
  const int*   dst  = (const int*)d_in[5];
  const float* Wmsg = (const float*)d_in[6];
  const float* Wq   = (const float*)d_in[7];
  const float* Wk   = (const float*)d_in[8];
  const float* Wout = (const float*)d_in[9];
  const float* gamma= (const float*)d_in[10];
  const float* beta = (const float*)d_in[11];
  float* out = (float*)d_out;

  int N = in_sizes[0] / 64;
  int E = in_sizes[4];

  char* ws = (char*)d_ws;
  size_t off = 0;
  auto alloc = [&](size_t bytes) -> void* {
    void* p = ws + off;
    off = (off + bytes + 255) & ~(size_t)255;
    return p;
  };
  float* g1  = (float*)alloc((size_t)N * 64 * 4);
  float* g2  = (float*)alloc((size_t)N * 64 * 4);
  float* hm  = (float*)alloc((size_t)N * 64 * 4);
  float* att = (float*)alloc((size_t)E * 4);
  float* A1T = (float*)alloc(4096 * 4);
  float* A2T = (float*)alloc(4096 * 4);
  float* M1T = (float*)alloc(4096 * 4);
  float* M2T = (float*)alloc(4096 * 4);
  unsigned int* deg    = (unsigned int*)alloc((size_t)N * 4);
  unsigned int* rowptr = (unsigned int*)alloc((size_t)(N + 1) * 4);
  unsigned int* cursor = (unsigned int*)alloc((size_t)N * 4);
  int* eidx = (int*)alloc((size_t)E * 4);

  hipMemsetAsync(deg, 0, (size_t)N * 4, stream);
  hipLaunchKernelGGL(k_setup, dim3(16), dim3(256), 0, stream, Wq, Wk, A1T, A2T, M1T, M2T);
  hipLaunchKernelGGL(k_node_pre, dim3(512), dim3(256), 0, stream, N, h, A1T, A2T, Wmsg, g1, g2, hm);
  hipLaunchKernelGGL(k_count, dim3(1024), dim3(256), 0, stream, E, dst, deg);
  hipLaunchKernelGGL(k_scan, dim3(1), dim3(1024), 0, stream, N, deg, rowptr, cursor);
  hipLaunchKernelGGL(k_edge, dim3(1024), dim3(256), 0, stream, E, eh, qrh, qeh, src, dst,
                     g1, g2, M1T, M2T, att, cursor, eidx);
  hipLaunchKernelGGL(k_node, dim3(1024), dim3(256), 0, stream, N, h, eh, src, hm, att,
                     rowptr, eidx, Wmsg, Wout, gamma, beta, out);
}